// Round 14
// baseline (181.803 us; speedup 1.0000x reference)
//
#include <hip/hip_runtime.h>
#include <hip/hip_bf16.h>
#include <stdint.h>

#define NB   8
#define NSEQ 4096
#define DIN  128
#define DK   64
#define DVV  128

typedef __bf16 bf16x8 __attribute__((ext_vector_type(8)));
typedef float f32x4 __attribute__((ext_vector_type(4)));
typedef float f32x16 __attribute__((ext_vector_type(16)));
typedef unsigned int u32x4v __attribute__((ext_vector_type(4)));
typedef unsigned short u16;
typedef unsigned int u32;

__device__ __forceinline__ u32 cvt_pk_bf16(float lo, float hi) {
  u32 r;
  asm("v_cvt_pk_bf16_f32 %0, %1, %2" : "=v"(r) : "v"(lo), "v"(hi));
  return r;
}

// async global->LDS, 16B/lane; LDS dest = wave-uniform base + lane*16 (HW rule)
#define GLDS16(G, L)                                                          \
  __builtin_amdgcn_global_load_lds(                                           \
      (__attribute__((address_space(1))) void*)(G),                           \
      (__attribute__((address_space(3))) void*)(L), 16, 0, 0)

// ---------------- projection via MFMA, single-pass x ----------------
// Workspace layouts are FRAGMENT-LINEAR for attn's 32x32x16 MFMA fragments:
//  Kf[b][t(128)][ks(4)][lane(64)][8]: lane (hi<<5)|m holds K[t*32+T[m]][ks*16+hi*8+j]
//    with T[(r&3)+8(r>>2)+4c] = (r>>3)*16 + c*8 + (r&7)  (QK A-operand, permuted
//    so S^T's C-regs land exactly as PV's B-fragment -> in-lane P pack).
//  Vf[b][t(128)][f=dt*2+s(8)][lane(64)][8]: lane c*32+row holds
//    V^T[dt*32+row][t*32 + s*16 + c*8 + j]  (PV A-operand).
__global__ __launch_bounds__(256) void proj(
    const float* __restrict__ x, const float* __restrict__ Wq,
    const float* __restrict__ Wk, const float* __restrict__ Wv,
    u16* __restrict__ Qb, u16* __restrict__ Kf, u16* __restrict__ Vf) {
  __shared__ alignas(16) u16 xs[64 * 128];
  const int tid = threadIdx.x;
  const int w = tid >> 6, l = tid & 63;
  const int lg = l >> 4, li = l & 15;
  const int b = blockIdx.x & 7;
  const int n0 = (blockIdx.x >> 3) << 6;

  {
    const float* xp = x + ((size_t)b * DIN + w * 32) * NSEQ + n0 + l;
    #pragma unroll
    for (int cc = 0; cc < 4; ++cc) {
      const int c = w * 4 + cc;
      u32 pk[4];
      #pragma unroll
      for (int jj = 0; jj < 4; ++jj) {
        const float f0 = xp[(size_t)(cc * 8 + 2 * jj) * NSEQ];
        const float f1 = xp[(size_t)(cc * 8 + 2 * jj + 1) * NSEQ];
        pk[jj] = cvt_pk_bf16(f0, f1);
      }
      *(uint4*)&xs[l * 128 + ((c ^ (l & 15)) * 8)] = *(uint4*)pk;
    }
  }

  const float* W;
  float scale = 1.0f;
  if (w == 0)      { W = Wq; scale = 0.180336880111120429f; }  // log2e/8
  else if (w == 1) { W = Wk; }
  else if (w == 2) { W = Wv; }
  else             { W = Wv + 64 * DIN; }

  bf16x8 wf[4][4];
  #pragma unroll
  for (int ct = 0; ct < 4; ++ct) {
    const float* wr = W + (ct * 16 + li) * DIN + lg * 8;
    #pragma unroll
    for (int ks = 0; ks < 4; ++ks) {
      const float4 f0 = *(const float4*)(wr + 32 * ks);
      const float4 f1 = *(const float4*)(wr + 32 * ks + 4);
      u32x4v pk;
      pk[0] = cvt_pk_bf16(f0.x * scale, f0.y * scale);
      pk[1] = cvt_pk_bf16(f0.z * scale, f0.w * scale);
      pk[2] = cvt_pk_bf16(f1.x * scale, f1.y * scale);
      pk[3] = cvt_pk_bf16(f1.z * scale, f1.w * scale);
      wf[ct][ks] = __builtin_bit_cast(bf16x8, pk);
    }
  }

  __syncthreads();

  const f32x4 fz = {0.f, 0.f, 0.f, 0.f};
  #pragma unroll
  for (int nt = 0; nt < 4; ++nt) {
    const int n16 = n0 + nt * 16;
    bf16x8 xf[4];
    #pragma unroll
    for (int ks = 0; ks < 4; ++ks)
      xf[ks] = *(const bf16x8*)&xs[(nt * 16 + li) * 128 + (((lg + 4 * ks) ^ li) * 8)];
    #pragma unroll
    for (int ct = 0; ct < 4; ++ct) {
      f32x4 acc = fz;
      if (w < 2) {
        #pragma unroll
        for (int ks = 0; ks < 4; ++ks)
          acc = __builtin_amdgcn_mfma_f32_16x16x32_bf16(xf[ks], wf[ct][ks], acc, 0, 0, 0);
        if (w == 0) {
          u16* ob = Qb + (size_t)b * NSEQ * DK;
          #pragma unroll
          for (int r = 0; r < 4; ++r)
            ob[(size_t)(n16 + lg * 4 + r) * DK + ct * 16 + li] =
                (u16)cvt_pk_bf16(acc[r], acc[r]);
        } else {
          // K fragment-linear (32x32 A-operand, T-permuted rows)
          #pragma unroll
          for (int r = 0; r < 4; ++r) {
            const int n = n16 + lg * 4 + r;           // kv row
            const int d = ct * 16 + li;               // k dim
            const int t = n >> 5, v = n & 31;
            const int s = v >> 4, c = (v >> 3) & 1, j = v & 7;
            const int m = (j & 3) + 16 * s + 8 * (j >> 2) + 4 * c;  // Tinv[v]
            const int hi = (d >> 3) & 1, ks = d >> 4, je = d & 7;
            Kf[((size_t)(b * 128 + t) * 4 + ks) * 512 + ((hi << 5) + m) * 8 + je] =
                (u16)cvt_pk_bf16(acc[r], acc[r]);
          }
        }
      } else {
        #pragma unroll
        for (int ks = 0; ks < 4; ++ks)
          acc = __builtin_amdgcn_mfma_f32_16x16x32_bf16(wf[ct][ks], xf[ks], acc, 0, 0, 0);
        const int chb = (w == 3 ? 64 : 0) + ct * 16 + lg * 4;
        // V fragment-linear (32x32 A-operand)
        #pragma unroll
        for (int r = 0; r < 4; ++r) {
          const int dv = chb + r;
          const int n = n16 + li;
          const int t = n >> 5, kv = n & 31;
          const int s = kv >> 4, c = (kv >> 3) & 1, j = kv & 7;
          const int dt = dv >> 5, row = dv & 31;
          Vf[((size_t)(b * 128 + t) * 8 + dt * 2 + s) * 512 + (c * 32 + row) * 8 + j] =
              (u16)cvt_pk_bf16(acc[r], acc[r]);
        }
      }
    }
  }
}

// ------- fused flash attention: 32x32x16 MFMA, kv-split-4, Wq=64, no main-loop barrier -------
// 512 blocks x 4 waves, wave-private kv quarter, KVBLK=32. Per iter: 8 QK + 16 PV
// = 24 MFMA (was 48 with 16x16x32) -> shorter serial chain, half the issue slots.
// S^T = mfma(K_perm, Q): C layout col=lane&31, row=(r&3)+8(r>>2)+4(lane>>5); the
// T-permutation makes reg r = s*8+j hold exactly PV's B-frag element (kv step s,
// elem j) -> in-lane cvt_pk pack, zero shuffles. Fixed-max softmax (shift-inv).
// V: 8x1KB global_load_lds / tile into private dbuf LDS; K: 4x1KB reg loads (L2).
__global__ __launch_bounds__(256, 2) void attn(
    const u16* __restrict__ Qb, const u16* __restrict__ Kf,
    const u16* __restrict__ Vf, const float* __restrict__ x,
    float* __restrict__ out) {
  __shared__ alignas(16) char lds[69632];
  const int tid = threadIdx.x;
  const int w = tid >> 6, l = tid & 63;
  const int lo5 = l & 31, hi5 = l >> 5;
  const int b = blockIdx.x & 7;
  const int qbase = (blockIdx.x >> 3) << 6;

  // Q B-fragments: qf[qt][ks]: col q = qbase + qt*32 + lo5, k = ks*16 + hi5*8 + j
  bf16x8 qf[2][4];
  #pragma unroll
  for (int qt = 0; qt < 2; ++qt) {
    const u16* qp = Qb + ((size_t)(b * NSEQ + qbase + qt * 32 + lo5)) * DK + hi5 * 8;
    #pragma unroll
    for (int ks = 0; ks < 4; ++ks)
      qf[qt][ks] = *(const bf16x8*)(qp + ks * 16);
  }

  f32x16 oacc[4][2];       // [dv-tile][q-tile], 128 f32 -> AGPRs
  #pragma unroll
  for (int dt = 0; dt < 4; ++dt)
    #pragma unroll
    for (int qt = 0; qt < 2; ++qt)
      #pragma unroll
      for (int r = 0; r < 16; ++r) oacc[dt][qt][r] = 0.f;
  const f32x16 z16 = oacc[0][0];
  float lrow[2] = {0.f, 0.f};

  const u16* kbase = Kf + (size_t)b * 128 * 2048 + l * 8;   // lane-linear
  const u16* vbase = Vf + (size_t)b * 128 * 4096 + l * 8;   // lane-linear
  char* const mybuf = lds + w * 16384;   // two private 8KB tiles

  bf16x8 kf[4];
#define KLOAD(T) do {                                                         \
    const u16* kp_ = kbase + (size_t)(T) * 2048;                              \
    _Pragma("unroll") for (int ks = 0; ks < 4; ++ks)                          \
      kf[ks] = *(const bf16x8*)(kp_ + ks * 512);                              \
  } while (0)
#define STAGEV(T, B) do {                                                     \
    char* vb_ = mybuf + (B) * 8192;                                           \
    const u16* vp_ = vbase + (size_t)(T) * 4096;                              \
    _Pragma("unroll") for (int f = 0; f < 8; ++f)                             \
      GLDS16(vp_ + f * 512, vb_ + f * 1024);                                  \
  } while (0)
#define BODY(T, CUR, PREFETCH) do {                                           \
    if (PREFETCH) STAGEV((T) + 1, (CUR) ^ 1);                                 \
    f32x16 s32[2];                                                            \
    __builtin_amdgcn_s_setprio(1);                                            \
    _Pragma("unroll") for (int qt = 0; qt < 2; ++qt) {                        \
      s32[qt] = __builtin_amdgcn_mfma_f32_32x32x16_bf16(kf[0], qf[qt][0], z16, 0, 0, 0); \
      s32[qt] = __builtin_amdgcn_mfma_f32_32x32x16_bf16(kf[1], qf[qt][1], s32[qt], 0, 0, 0); \
      s32[qt] = __builtin_amdgcn_mfma_f32_32x32x16_bf16(kf[2], qf[qt][2], s32[qt], 0, 0, 0); \
      s32[qt] = __builtin_amdgcn_mfma_f32_32x32x16_bf16(kf[3], qf[qt][3], s32[qt], 0, 0, 0); \
    }                                                                         \
    __builtin_amdgcn_s_setprio(0);                                            \
    if (PREFETCH) KLOAD((T) + 1);                                             \
    bf16x8 pf[2][2];                                                          \
    _Pragma("unroll") for (int qt = 0; qt < 2; ++qt) {                        \
      float pa[16];                                                           \
      _Pragma("unroll") for (int r = 0; r < 16; ++r)                          \
        pa[r] = __builtin_amdgcn_exp2f(s32[qt][r]);                           \
      lrow[qt] += (((pa[0] + pa[1]) + (pa[2] + pa[3])) +                      \
                   ((pa[4] + pa[5]) + (pa[6] + pa[7]))) +                     \
                  (((pa[8] + pa[9]) + (pa[10] + pa[11])) +                    \
                   ((pa[12] + pa[13]) + (pa[14] + pa[15])));                  \
      u32x4v pk0, pk1;                                                        \
      pk0[0] = cvt_pk_bf16(pa[0], pa[1]);                                     \
      pk0[1] = cvt_pk_bf16(pa[2], pa[3]);                                     \
      pk0[2] = cvt_pk_bf16(pa[4], pa[5]);                                     \
      pk0[3] = cvt_pk_bf16(pa[6], pa[7]);                                     \
      pk1[0] = cvt_pk_bf16(pa[8], pa[9]);                                     \
      pk1[1] = cvt_pk_bf16(pa[10], pa[11]);                                   \
      pk1[2] = cvt_pk_bf16(pa[12], pa[13]);                                   \
      pk1[3] = cvt_pk_bf16(pa[14], pa[15]);                                   \
      pf[qt][0] = __builtin_bit_cast(bf16x8, pk0);                            \
      pf[qt][1] = __builtin_bit_cast(bf16x8, pk1);                            \
    }                                                                         \
    asm volatile("s_waitcnt vmcnt(12)" ::: "memory");                         \
    const char* vb = mybuf + (CUR) * 8192;                                    \
    __builtin_amdgcn_s_setprio(1);                                            \
    _Pragma("unroll") for (int dt = 0; dt < 4; ++dt) {                        \
      _Pragma("unroll") for (int s = 0; s < 2; ++s) {                         \
        const bf16x8 vf = *(const bf16x8*)(vb + (dt * 2 + s) * 1024 + l * 16);\
        _Pragma("unroll") for (int qt = 0; qt < 2; ++qt)                      \
          oacc[dt][qt] = __builtin_amdgcn_mfma_f32_32x32x16_bf16(             \
              vf, pf[qt][s], oacc[dt][qt], 0, 0, 0);                          \
      }                                                                       \
    }                                                                         \
    __builtin_amdgcn_s_setprio(0);                                            \
  } while (0)

  const int t0 = w * 32;                 // this wave's first kv tile
  STAGEV(t0, 0);                         // V(t) always issued BEFORE K(t)
  KLOAD(t0);

  #pragma unroll 2
  for (int i = 0; i < 31; ++i) {
    BODY(t0 + i, i & 1, 1);
  }
  BODY(t0 + 31, 1, 0);                   // peeled final iteration

  // ---- epilogue: 4-partial merge tree (the only barriers) ----
  #pragma unroll
  for (int qt = 0; qt < 2; ++qt)
    lrow[qt] += __shfl_xor(lrow[qt], 32, 64);   // other kv-half, same q col
  float* const bufA = (float*)lds;                 // [128 dv][67] f32
  float* const bufB = (float*)(lds + 34304);       // [128 dv][67] f32
  float* const stats = (float*)(lds + 68608);      // [4 w][2 qt][32 q]
#define DUMP(DST) do {                                                        \
    _Pragma("unroll") for (int dt = 0; dt < 4; ++dt)                          \
      _Pragma("unroll") for (int qt = 0; qt < 2; ++qt)                        \
        _Pragma("unroll") for (int r = 0; r < 16; ++r)                        \
          (DST)[(dt * 32 + (r & 3) + 8 * (r >> 2) + 4 * hi5) * 67 +           \
                qt * 32 + lo5] = oacc[dt][qt][r];                             \
  } while (0)
#define ADDF(SRC) do {                                                        \
    _Pragma("unroll") for (int dt = 0; dt < 4; ++dt)                          \
      _Pragma("unroll") for (int qt = 0; qt < 2; ++qt)                        \
        _Pragma("unroll") for (int r = 0; r < 16; ++r)                        \
          oacc[dt][qt][r] += (SRC)[(dt * 32 + (r & 3) + 8 * (r >> 2) + 4 * hi5) * 67 + \
                                   qt * 32 + lo5];                            \
  } while (0)
#define SAVESTATS(WI) do {                                                    \
    if (l < 32) {                                                             \
      for (int qt = 0; qt < 2; ++qt)                                          \
        stats[(WI) * 64 + qt * 32 + lo5] = lrow[qt];                          \
    }                                                                         \
  } while (0)
  __syncthreads();                        // V bufs dead; epilogue regions live
  if (w == 1) { DUMP(bufA); SAVESTATS(1); }
  if (w == 3) { DUMP(bufB); SAVESTATS(3); }
  __syncthreads();
  if (w == 0) ADDF(bufA);
  if (w == 2) {
    ADDF(bufB);
    #pragma unroll
    for (int qt = 0; qt < 2; ++qt) lrow[qt] += stats[3 * 64 + qt * 32 + lo5];
  }
  __syncthreads();
  if (w == 2) { DUMP(bufA); SAVESTATS(2); }
  __syncthreads();
  if (w == 0) {
    ADDF(bufA);
    #pragma unroll
    for (int qt = 0; qt < 2; ++qt) {
      const float ls = lrow[qt] + stats[1 * 64 + qt * 32 + lo5]
                                + stats[2 * 64 + qt * 32 + lo5];
      const float rl = 1.0f / ls;
      #pragma unroll
      for (int dt = 0; dt < 4; ++dt) {
        #pragma unroll
        for (int r = 0; r < 16; ++r) {
          const int dv = dt * 32 + (r & 3) + 8 * (r >> 2) + 4 * hi5;
          const size_t idx = ((size_t)b * DVV + dv) * NSEQ + qbase + qt * 32 + lo5;
          out[idx] = oacc[dt][qt][r] * rl + x[idx];
        }
      }
    }
  }
#undef KLOAD
#undef STAGEV
#undef BODY
#undef DUMP
#undef ADDF
#undef SAVESTATS
}

extern "C" void kernel_launch(void* const* d_in, const int* in_sizes, int n_in,
                              void* d_out, int out_size, void* d_ws, size_t ws_size,
                              hipStream_t stream) {
  const float* x  = (const float*)d_in[0];
  const float* Wq = (const float*)d_in[1];
  const float* Wk = (const float*)d_in[2];
  const float* Wv = (const float*)d_in[3];
  float* out = (float*)d_out;

  u16* qws = (u16*)d_ws;                                   // [8][4096][64]   4MB
  u16* kws = qws + (size_t)NB * NSEQ * DK;                 // Kf frag-linear  4MB
  u16* vws = kws + (size_t)NB * NSEQ * DK;                 // Vf frag-linear  8MB

  proj<<<512, 256, 0, stream>>>(x, Wq, Wk, Wv, qws, kws, vws);
  attn<<<512, 256, 0, stream>>>(qws, kws, vws, x, out);
}

// Round 15
// 114.655 us; speedup vs baseline: 1.5857x; 1.5857x over previous
//
#include <hip/hip_runtime.h>
#include <hip/hip_bf16.h>
#include <stdint.h>

#define NB   8
#define NSEQ 4096
#define DIN  128
#define DK   64
#define DVV  128

typedef __bf16 bf16x8 __attribute__((ext_vector_type(8)));
typedef float f32x4 __attribute__((ext_vector_type(4)));
typedef float f32x16 __attribute__((ext_vector_type(16)));
typedef unsigned int u32x4v __attribute__((ext_vector_type(4)));
typedef unsigned short u16;
typedef unsigned int u32;

__device__ __forceinline__ u32 cvt_pk_bf16(float lo, float hi) {
  u32 r;
  asm("v_cvt_pk_bf16_f32 %0, %1, %2" : "=v"(r) : "v"(lo), "v"(hi));
  return r;
}

// async global->LDS, 16B/lane; LDS dest = wave-uniform base + lane*16 (HW rule)
#define GLDS16(G, L)                                                          \
  __builtin_amdgcn_global_load_lds(                                           \
      (__attribute__((address_space(1))) void*)(G),                           \
      (__attribute__((address_space(3))) void*)(L), 16, 0, 0)

// ---------------- projection via MFMA, single-pass x (verified round 14) ----------
// Fragment-linear workspace for attn's 32x32x16 fragments:
//  Kf[b][t][ks(4)][lane][8]: lane (hi<<5)|m holds K[t*32+T[m]][ks*16+hi*8+j],
//    T[(r&3)+8(r>>2)+4c] = (r>>3)*16 + c*8 + (r&7).
//  Vf[b][t][f=dt*2+s][lane][8]: lane c*32+row holds V^T[dt*32+row][t*32+s*16+c*8+j].
__global__ __launch_bounds__(256) void proj(
    const float* __restrict__ x, const float* __restrict__ Wq,
    const float* __restrict__ Wk, const float* __restrict__ Wv,
    u16* __restrict__ Qb, u16* __restrict__ Kf, u16* __restrict__ Vf) {
  __shared__ alignas(16) u16 xs[64 * 128];
  const int tid = threadIdx.x;
  const int w = tid >> 6, l = tid & 63;
  const int lg = l >> 4, li = l & 15;
  const int b = blockIdx.x & 7;
  const int n0 = (blockIdx.x >> 3) << 6;

  {
    const float* xp = x + ((size_t)b * DIN + w * 32) * NSEQ + n0 + l;
    #pragma unroll
    for (int cc = 0; cc < 4; ++cc) {
      const int c = w * 4 + cc;
      u32 pk[4];
      #pragma unroll
      for (int jj = 0; jj < 4; ++jj) {
        const float f0 = xp[(size_t)(cc * 8 + 2 * jj) * NSEQ];
        const float f1 = xp[(size_t)(cc * 8 + 2 * jj + 1) * NSEQ];
        pk[jj] = cvt_pk_bf16(f0, f1);
      }
      *(uint4*)&xs[l * 128 + ((c ^ (l & 15)) * 8)] = *(uint4*)pk;
    }
  }

  const float* W;
  float scale = 1.0f;
  if (w == 0)      { W = Wq; scale = 0.180336880111120429f; }  // log2e/8
  else if (w == 1) { W = Wk; }
  else if (w == 2) { W = Wv; }
  else             { W = Wv + 64 * DIN; }

  bf16x8 wf[4][4];
  #pragma unroll
  for (int ct = 0; ct < 4; ++ct) {
    const float* wr = W + (ct * 16 + li) * DIN + lg * 8;
    #pragma unroll
    for (int ks = 0; ks < 4; ++ks) {
      const float4 f0 = *(const float4*)(wr + 32 * ks);
      const float4 f1 = *(const float4*)(wr + 32 * ks + 4);
      u32x4v pk;
      pk[0] = cvt_pk_bf16(f0.x * scale, f0.y * scale);
      pk[1] = cvt_pk_bf16(f0.z * scale, f0.w * scale);
      pk[2] = cvt_pk_bf16(f1.x * scale, f1.y * scale);
      pk[3] = cvt_pk_bf16(f1.z * scale, f1.w * scale);
      wf[ct][ks] = __builtin_bit_cast(bf16x8, pk);
    }
  }

  __syncthreads();

  const f32x4 fz = {0.f, 0.f, 0.f, 0.f};
  #pragma unroll
  for (int nt = 0; nt < 4; ++nt) {
    const int n16 = n0 + nt * 16;
    bf16x8 xf[4];
    #pragma unroll
    for (int ks = 0; ks < 4; ++ks)
      xf[ks] = *(const bf16x8*)&xs[(nt * 16 + li) * 128 + (((lg + 4 * ks) ^ li) * 8)];
    #pragma unroll
    for (int ct = 0; ct < 4; ++ct) {
      f32x4 acc = fz;
      if (w < 2) {
        #pragma unroll
        for (int ks = 0; ks < 4; ++ks)
          acc = __builtin_amdgcn_mfma_f32_16x16x32_bf16(xf[ks], wf[ct][ks], acc, 0, 0, 0);
        if (w == 0) {
          u16* ob = Qb + (size_t)b * NSEQ * DK;
          #pragma unroll
          for (int r = 0; r < 4; ++r)
            ob[(size_t)(n16 + lg * 4 + r) * DK + ct * 16 + li] =
                (u16)cvt_pk_bf16(acc[r], acc[r]);
        } else {
          #pragma unroll
          for (int r = 0; r < 4; ++r) {
            const int n = n16 + lg * 4 + r;           // kv row
            const int d = ct * 16 + li;               // k dim
            const int t = n >> 5, v = n & 31;
            const int s = v >> 4, c = (v >> 3) & 1, j = v & 7;
            const int m = (j & 3) + 16 * s + 8 * (j >> 2) + 4 * c;  // Tinv[v]
            const int hi = (d >> 3) & 1, ks = d >> 4, je = d & 7;
            Kf[((size_t)(b * 128 + t) * 4 + ks) * 512 + ((hi << 5) + m) * 8 + je] =
                (u16)cvt_pk_bf16(acc[r], acc[r]);
          }
        }
      } else {
        #pragma unroll
        for (int ks = 0; ks < 4; ++ks)
          acc = __builtin_amdgcn_mfma_f32_16x16x32_bf16(wf[ct][ks], xf[ks], acc, 0, 0, 0);
        const int chb = (w == 3 ? 64 : 0) + ct * 16 + lg * 4;
        #pragma unroll
        for (int r = 0; r < 4; ++r) {
          const int dv = chb + r;
          const int n = n16 + li;
          const int t = n >> 5, kv = n & 31;
          const int s = kv >> 4, c = (kv >> 3) & 1, j = kv & 7;
          const int dt = dv >> 5, row = dv & 31;
          Vf[((size_t)(b * 128 + t) * 8 + dt * 2 + s) * 512 + (c * 32 + row) * 8 + j] =
              (u16)cvt_pk_bf16(acc[r], acc[r]);
        }
      }
    }
  }
}

// ------- fused flash attention: 32x32x16 MFMA, qt-sequential (liveness-controlled) -------
// 512 blocks x 4 waves, wave-private kv quarter, KVBLK=32, no main-loop barrier.
// Per iter: 8 QK + 16 PV = 24 MFMA. Pipeline per iter:
//   STAGEV(t+1) ; QK(qt0) ; SM(qt0) ; QK(qt1) ; KLOAD(t+1) ; SM(qt1) ; vmcnt ; PV
// Only ONE 16-reg S tile live at a time (round-14 spill fix); unroll 1.
// SM(qt0) VALU can overlap QK(qt1) MFMA (independent) -> intra-wave pipe overlap.
__global__ __launch_bounds__(256, 2) void attn(
    const u16* __restrict__ Qb, const u16* __restrict__ Kf,
    const u16* __restrict__ Vf, const float* __restrict__ x,
    float* __restrict__ out) {
  __shared__ alignas(16) char lds[69632];
  const int tid = threadIdx.x;
  const int w = tid >> 6, l = tid & 63;
  const int lo5 = l & 31, hi5 = l >> 5;
  const int b = blockIdx.x & 7;
  const int qbase = (blockIdx.x >> 3) << 6;

  // Q B-fragments: qf[qt][ks]: col q = qbase + qt*32 + lo5, k = ks*16 + hi5*8 + j
  bf16x8 qf[2][4];
  #pragma unroll
  for (int qt = 0; qt < 2; ++qt) {
    const u16* qp = Qb + ((size_t)(b * NSEQ + qbase + qt * 32 + lo5)) * DK + hi5 * 8;
    #pragma unroll
    for (int ks = 0; ks < 4; ++ks)
      qf[qt][ks] = *(const bf16x8*)(qp + ks * 16);
  }

  f32x16 z16;
  #pragma unroll
  for (int r = 0; r < 16; ++r) z16[r] = 0.f;
  f32x16 oacc[4][2];       // [dv-tile][q-tile], 128 f32 -> AGPRs
  #pragma unroll
  for (int dt = 0; dt < 4; ++dt)
    #pragma unroll
    for (int qt = 0; qt < 2; ++qt) oacc[dt][qt] = z16;
  float lrow[2] = {0.f, 0.f};

  const u16* kbase = Kf + (size_t)b * 128 * 2048 + l * 8;   // lane-linear
  const u16* vbase = Vf + (size_t)b * 128 * 4096 + l * 8;   // lane-linear
  char* const mybuf = lds + w * 16384;   // two private 8KB tiles

  bf16x8 kf[4];
  bf16x8 pf[2][2];
#define KLOAD(T) do {                                                         \
    const u16* kp_ = kbase + (size_t)(T) * 2048;                              \
    _Pragma("unroll") for (int ks = 0; ks < 4; ++ks)                          \
      kf[ks] = *(const bf16x8*)(kp_ + ks * 512);                              \
  } while (0)
#define STAGEV(T, B) do {                                                     \
    char* vb_ = mybuf + (B) * 8192;                                           \
    const u16* vp_ = vbase + (size_t)(T) * 4096;                              \
    _Pragma("unroll") for (int f = 0; f < 8; ++f)                             \
      GLDS16(vp_ + f * 512, vb_ + f * 1024);                                  \
  } while (0)
// QK chain for one q-tile into DST (16 regs, freed by following SM)
#define QK(QT, DST) do {                                                      \
    __builtin_amdgcn_s_setprio(1);                                            \
    DST = __builtin_amdgcn_mfma_f32_32x32x16_bf16(kf[0], qf[QT][0], z16, 0, 0, 0); \
    DST = __builtin_amdgcn_mfma_f32_32x32x16_bf16(kf[1], qf[QT][1], DST, 0, 0, 0); \
    DST = __builtin_amdgcn_mfma_f32_32x32x16_bf16(kf[2], qf[QT][2], DST, 0, 0, 0); \
    DST = __builtin_amdgcn_mfma_f32_32x32x16_bf16(kf[3], qf[QT][3], DST, 0, 0, 0); \
    __builtin_amdgcn_s_setprio(0);                                            \
  } while (0)
// fixed-max softmax + in-lane P pack (reg r = s*8+j == PV B-frag layout)
#define SM(QT, SRC) do {                                                      \
    float pa[16];                                                             \
    _Pragma("unroll") for (int r = 0; r < 16; ++r)                            \
      pa[r] = __builtin_amdgcn_exp2f(SRC[r]);                                 \
    lrow[QT] += (((pa[0] + pa[1]) + (pa[2] + pa[3])) +                        \
                 ((pa[4] + pa[5]) + (pa[6] + pa[7]))) +                       \
                (((pa[8] + pa[9]) + (pa[10] + pa[11])) +                      \
                 ((pa[12] + pa[13]) + (pa[14] + pa[15])));                    \
    u32x4v pk0, pk1;                                                          \
    pk0[0] = cvt_pk_bf16(pa[0], pa[1]);                                       \
    pk0[1] = cvt_pk_bf16(pa[2], pa[3]);                                       \
    pk0[2] = cvt_pk_bf16(pa[4], pa[5]);                                       \
    pk0[3] = cvt_pk_bf16(pa[6], pa[7]);                                       \
    pk1[0] = cvt_pk_bf16(pa[8], pa[9]);                                       \
    pk1[1] = cvt_pk_bf16(pa[10], pa[11]);                                     \
    pk1[2] = cvt_pk_bf16(pa[12], pa[13]);                                     \
    pk1[3] = cvt_pk_bf16(pa[14], pa[15]);                                     \
    pf[QT][0] = __builtin_bit_cast(bf16x8, pk0);                              \
    pf[QT][1] = __builtin_bit_cast(bf16x8, pk1);                              \
  } while (0)
#define BODY(T, CUR, PREFETCH) do {                                           \
    if (PREFETCH) STAGEV((T) + 1, (CUR) ^ 1);                                 \
    {                                                                         \
      f32x16 sA;                                                              \
      QK(0, sA);                                                              \
      SM(0, sA);                                                              \
    }                                                                         \
    {                                                                         \
      f32x16 sB;                                                              \
      QK(1, sB);                                                              \
      if (PREFETCH) KLOAD((T) + 1);                                           \
      SM(1, sB);                                                              \
    }                                                                         \
    asm volatile("s_waitcnt vmcnt(12)" ::: "memory");                         \
    const char* vb = mybuf + (CUR) * 8192;                                    \
    __builtin_amdgcn_s_setprio(1);                                            \
    _Pragma("unroll") for (int dt = 0; dt < 4; ++dt) {                        \
      _Pragma("unroll") for (int s = 0; s < 2; ++s) {                         \
        const bf16x8 vf = *(const bf16x8*)(vb + (dt * 2 + s) * 1024 + l * 16);\
        _Pragma("unroll") for (int qt = 0; qt < 2; ++qt)                      \
          oacc[dt][qt] = __builtin_amdgcn_mfma_f32_32x32x16_bf16(             \
              vf, pf[qt][s], oacc[dt][qt], 0, 0, 0);                          \
      }                                                                       \
    }                                                                         \
    __builtin_amdgcn_s_setprio(0);                                            \
  } while (0)

  const int t0 = w * 32;                 // this wave's first kv tile
  STAGEV(t0, 0);                         // V(t) always issued BEFORE K(t)
  KLOAD(t0);

  #pragma unroll 1
  for (int i = 0; i < 31; ++i) {
    BODY(t0 + i, i & 1, 1);
  }
  BODY(t0 + 31, 1, 0);                   // peeled final iteration

  // ---- epilogue: 4-partial merge tree (the only barriers) ----
  #pragma unroll
  for (int qt = 0; qt < 2; ++qt)
    lrow[qt] += __shfl_xor(lrow[qt], 32, 64);   // other kv-half, same q col
  float* const bufA = (float*)lds;                 // [128 dv][67] f32
  float* const bufB = (float*)(lds + 34304);       // [128 dv][67] f32
  float* const stats = (float*)(lds + 68608);      // [4 w][2 qt][32 q]
#define DUMP(DST) do {                                                        \
    _Pragma("unroll") for (int dt = 0; dt < 4; ++dt)                          \
      _Pragma("unroll") for (int qt = 0; qt < 2; ++qt)                        \
        _Pragma("unroll") for (int r = 0; r < 16; ++r)                        \
          (DST)[(dt * 32 + (r & 3) + 8 * (r >> 2) + 4 * hi5) * 67 +           \
                qt * 32 + lo5] = oacc[dt][qt][r];                             \
  } while (0)
#define ADDF(SRC) do {                                                        \
    _Pragma("unroll") for (int dt = 0; dt < 4; ++dt)                          \
      _Pragma("unroll") for (int qt = 0; qt < 2; ++qt)                        \
        _Pragma("unroll") for (int r = 0; r < 16; ++r)                        \
          oacc[dt][qt][r] += (SRC)[(dt * 32 + (r & 3) + 8 * (r >> 2) + 4 * hi5) * 67 + \
                                   qt * 32 + lo5];                            \
  } while (0)
#define SAVESTATS(WI) do {                                                    \
    if (l < 32) {                                                             \
      for (int qt = 0; qt < 2; ++qt)                                          \
        stats[(WI) * 64 + qt * 32 + lo5] = lrow[qt];                          \
    }                                                                         \
  } while (0)
  __syncthreads();                        // V bufs dead; epilogue regions live
  if (w == 1) { DUMP(bufA); SAVESTATS(1); }
  if (w == 3) { DUMP(bufB); SAVESTATS(3); }
  __syncthreads();
  if (w == 0) ADDF(bufA);
  if (w == 2) {
    ADDF(bufB);
    #pragma unroll
    for (int qt = 0; qt < 2; ++qt) lrow[qt] += stats[3 * 64 + qt * 32 + lo5];
  }
  __syncthreads();
  if (w == 2) { DUMP(bufA); SAVESTATS(2); }
  __syncthreads();
  if (w == 0) {
    ADDF(bufA);
    #pragma unroll
    for (int qt = 0; qt < 2; ++qt) {
      const float ls = lrow[qt] + stats[1 * 64 + qt * 32 + lo5]
                                + stats[2 * 64 + qt * 32 + lo5];
      const float rl = 1.0f / ls;
      #pragma unroll
      for (int dt = 0; dt < 4; ++dt) {
        #pragma unroll
        for (int r = 0; r < 16; ++r) {
          const int dv = dt * 32 + (r & 3) + 8 * (r >> 2) + 4 * hi5;
          const size_t idx = ((size_t)b * DVV + dv) * NSEQ + qbase + qt * 32 + lo5;
          out[idx] = oacc[dt][qt][r] * rl + x[idx];
        }
      }
    }
  }
#undef KLOAD
#undef STAGEV
#undef QK
#undef SM
#undef BODY
#undef DUMP
#undef ADDF
#undef SAVESTATS
}

extern "C" void kernel_launch(void* const* d_in, const int* in_sizes, int n_in,
                              void* d_out, int out_size, void* d_ws, size_t ws_size,
                              hipStream_t stream) {
  const float* x  = (const float*)d_in[0];
  const float* Wq = (const float*)d_in[1];
  const float* Wk = (const float*)d_in[2];
  const float* Wv = (const float*)d_in[3];
  float* out = (float*)d_out;

  u16* qws = (u16*)d_ws;                                   // [8][4096][64]   4MB
  u16* kws = qws + (size_t)NB * NSEQ * DK;                 // Kf frag-linear  4MB
  u16* vws = kws + (size_t)NB * NSEQ * DK;                 // Vf frag-linear  8MB

  proj<<<512, 256, 0, stream>>>(x, Wq, Wk, Wv, qws, kws, vws);
  attn<<<512, 256, 0, stream>>>(qws, kws, vws, x, out);
}

// Round 16
// 90.758 us; speedup vs baseline: 2.0032x; 1.2633x over previous
//
#include <hip/hip_runtime.h>
#include <hip/hip_bf16.h>
#include <stdint.h>

#define NB   8
#define NSEQ 4096
#define DIN  128
#define DK   64
#define DVV  128

typedef __bf16 bf16x8 __attribute__((ext_vector_type(8)));
typedef float f32x4 __attribute__((ext_vector_type(4)));
typedef unsigned int u32x4v __attribute__((ext_vector_type(4)));
typedef unsigned short u16;
typedef unsigned int u32;

__device__ __forceinline__ u32 cvt_pk_bf16(float lo, float hi) {
  u32 r;
  asm("v_cvt_pk_bf16_f32 %0, %1, %2" : "=v"(r) : "v"(lo), "v"(hi));
  return r;
}

// async global->LDS, 16B/lane; LDS dest = wave-uniform base + lane*16 (HW rule)
#define GLDS16(G, L)                                                          \
  __builtin_amdgcn_global_load_lds(                                           \
      (__attribute__((address_space(1))) void*)(G),                           \
      (__attribute__((address_space(3))) void*)(L), 16, 0, 0)

// ---------------- projection via MFMA, single-pass x (verbatim round 13) ----------
// Fragment-linear K/V workspace layouts (attn's exact lane order):
//   Kf[b][t(128)][jt*2+kc][lane][8], Vf[b][t(128)][slot][lp][8],
//   lp = (dv&7) | ((kv>>3)<<3) | (((dv>>3)&1)<<5).
__global__ __launch_bounds__(256) void proj(
    const float* __restrict__ x, const float* __restrict__ Wq,
    const float* __restrict__ Wk, const float* __restrict__ Wv,
    u16* __restrict__ Qb, u16* __restrict__ Kf, u16* __restrict__ Vf) {
  __shared__ alignas(16) u16 xs[64 * 128];
  const int tid = threadIdx.x;
  const int w = tid >> 6, l = tid & 63;
  const int lg = l >> 4, li = l & 15;
  const int b = blockIdx.x & 7;
  const int n0 = (blockIdx.x >> 3) << 6;

  {
    const float* xp = x + ((size_t)b * DIN + w * 32) * NSEQ + n0 + l;
    #pragma unroll
    for (int cc = 0; cc < 4; ++cc) {
      const int c = w * 4 + cc;
      u32 pk[4];
      #pragma unroll
      for (int jj = 0; jj < 4; ++jj) {
        const float f0 = xp[(size_t)(cc * 8 + 2 * jj) * NSEQ];
        const float f1 = xp[(size_t)(cc * 8 + 2 * jj + 1) * NSEQ];
        pk[jj] = cvt_pk_bf16(f0, f1);
      }
      *(uint4*)&xs[l * 128 + ((c ^ (l & 15)) * 8)] = *(uint4*)pk;
    }
  }

  const float* W;
  float scale = 1.0f;
  if (w == 0)      { W = Wq; scale = 0.180336880111120429f; }  // log2e/8
  else if (w == 1) { W = Wk; }
  else if (w == 2) { W = Wv; }
  else             { W = Wv + 64 * DIN; }

  bf16x8 wf[4][4];
  #pragma unroll
  for (int ct = 0; ct < 4; ++ct) {
    const float* wr = W + (ct * 16 + li) * DIN + lg * 8;
    #pragma unroll
    for (int ks = 0; ks < 4; ++ks) {
      const float4 f0 = *(const float4*)(wr + 32 * ks);
      const float4 f1 = *(const float4*)(wr + 32 * ks + 4);
      u32x4v pk;
      pk[0] = cvt_pk_bf16(f0.x * scale, f0.y * scale);
      pk[1] = cvt_pk_bf16(f0.z * scale, f0.w * scale);
      pk[2] = cvt_pk_bf16(f1.x * scale, f1.y * scale);
      pk[3] = cvt_pk_bf16(f1.z * scale, f1.w * scale);
      wf[ct][ks] = __builtin_bit_cast(bf16x8, pk);
    }
  }

  __syncthreads();

  const f32x4 fz = {0.f, 0.f, 0.f, 0.f};
  #pragma unroll
  for (int nt = 0; nt < 4; ++nt) {
    const int n16 = n0 + nt * 16;
    bf16x8 xf[4];
    #pragma unroll
    for (int ks = 0; ks < 4; ++ks)
      xf[ks] = *(const bf16x8*)&xs[(nt * 16 + li) * 128 + (((lg + 4 * ks) ^ li) * 8)];
    #pragma unroll
    for (int ct = 0; ct < 4; ++ct) {
      f32x4 acc = fz;
      if (w < 2) {
        #pragma unroll
        for (int ks = 0; ks < 4; ++ks)
          acc = __builtin_amdgcn_mfma_f32_16x16x32_bf16(xf[ks], wf[ct][ks], acc, 0, 0, 0);
        if (w == 0) {
          u16* ob = Qb + (size_t)b * NSEQ * DK;
          #pragma unroll
          for (int r = 0; r < 4; ++r)
            ob[(size_t)(n16 + lg * 4 + r) * DK + ct * 16 + li] =
                (u16)cvt_pk_bf16(acc[r], acc[r]);
        } else {
          #pragma unroll
          for (int r = 0; r < 4; ++r) {
            const int n = n16 + lg * 4 + r;           // kv row
            const int d = ct * 16 + li;               // k dim
            const int t = n >> 5, rowin = n & 31;
            const int jt = (rowin >> 2) & 1;
            const int lip = 4 * (rowin >> 3) + (rowin & 3);
            const int kc = d >> 5;
            const int lgp = (d & 31) >> 3;
            Kf[((size_t)(b * 128 + t) * 4 + (jt * 2 + kc)) * 512 +
               (lgp * 16 + lip) * 8 + (d & 7)] = (u16)cvt_pk_bf16(acc[r], acc[r]);
          }
        }
      } else {
        #pragma unroll
        for (int ks = 0; ks < 4; ++ks)
          acc = __builtin_amdgcn_mfma_f32_16x16x32_bf16(wf[ct][ks], xf[ks], acc, 0, 0, 0);
        const int chb = (w == 3 ? 64 : 0) + ct * 16 + lg * 4;
        #pragma unroll
        for (int r = 0; r < 4; ++r) {
          const int dv = chb + r;
          const int n = n16 + li;
          const int t = n >> 5, kv = n & 31;
          const int s = dv >> 4;
          const int lp = (dv & 7) | ((kv >> 3) << 3) | (((dv >> 3) & 1) << 5);
          Vf[((size_t)(b * 128 + t) * 8 + s) * 512 + lp * 8 + (kv & 7)] =
              (u16)cvt_pk_bf16(acc[r], acc[r]);
        }
      }
    }
  }
}

// ------- fused flash attention: q-split x kv-split, 3 waves/SIMD target -------
// 512 blocks (b(8)=XCD x qg(64)) x 4 waves: wave w -> qw = w>>1 (q-half, 32 q),
// kvh = w&1 (kv-half, 64 tiles of 32). oacc = 64 regs (half of r13) -> est ~150
// total regs -> 3 waves/SIMD, 3 blocks/CU = 12 waves/CU (r13 had 8).
// V: staged ONCE per (block,kvh) into shared dbuf (2x8KB per kvh, 32KB total);
// the two q-waves of a kvh each stage 4 of 8 slots. Sync = counted vmcnt(4) +
// RAW s_barrier per iter (no vmcnt(0) drain -> prefetches fly across barrier).
// K: 4x1KB frag-linear reg loads (dup x2 across q-waves; same-CU L1 absorbs).
// QK/SM/PV identical math to r13 (verified): K T-permutation -> in-lane P pack,
// fixed-max softmax. Epilogue: per-qw pair merge (pure adds) + residual.
__global__ __launch_bounds__(256, 3) void attn(
    const u16* __restrict__ Qb, const u16* __restrict__ Kf,
    const u16* __restrict__ Vf, const float* __restrict__ x,
    float* __restrict__ out) {
  __shared__ alignas(16) char lds[34816];  // main 32KB; epi 2x16896 + 256B stats
  const int tid = threadIdx.x;
  const int w = tid >> 6, l = tid & 63;
  const int lg = l >> 4, li = l & 15;
  const int qw = w >> 1, kvh = w & 1;
  const int b = blockIdx.x & 7;
  const int qbase = ((blockIdx.x >> 3) << 6) + qw * 32;

  // Q B-fragments: qf[h][kc]: col q = qbase+16h+li, k = kc*32 + lg*8 + j
  bf16x8 qf[2][2];
  #pragma unroll
  for (int h = 0; h < 2; ++h) {
    const u16* qp = Qb + ((size_t)(b * NSEQ + qbase + h * 16 + li) * DK + lg * 8);
    qf[h][0] = *(const bf16x8*)qp;
    qf[h][1] = *(const bf16x8*)(qp + 32);
  }

  const f32x4 fzero = {0.f, 0.f, 0.f, 0.f};
  f32x4 oacc[2][8];
  #pragma unroll
  for (int h = 0; h < 2; ++h)
    #pragma unroll
    for (int dt = 0; dt < 8; ++dt) oacc[h][dt] = fzero;
  float lrow[2] = {0.f, 0.f};

  const u16* kbase = Kf + (size_t)b * 128 * 2048 + l * 8;   // lane-linear
  const u16* vbase = Vf + (size_t)b * 128 * 4096 + l * 8;   // lane-linear
  char* const vlds = lds + kvh * 16384;     // this kv-half's shared dbuf
  const int qs4 = qw * 4;                   // this wave's 4 staging slots
  const int vq = (((li & 7) | (lg << 3) | ((li >> 3) << 5)) << 4);

  bf16x8 kf[2][2];
#define KLOAD(T) do {                                                         \
    const u16* kp_ = kbase + (size_t)(T) * 2048;                              \
    _Pragma("unroll") for (int jt = 0; jt < 2; ++jt)                          \
      _Pragma("unroll") for (int kc = 0; kc < 2; ++kc)                        \
        kf[jt][kc] = *(const bf16x8*)(kp_ + (jt * 2 + kc) * 512);             \
  } while (0)
#define STAGEV(T, B) do {                                                     \
    char* vb_ = vlds + (B) * 8192;                                            \
    const u16* vp_ = vbase + (size_t)(T) * 4096;                              \
    _Pragma("unroll") for (int f = 0; f < 4; ++f)                             \
      GLDS16(vp_ + (qs4 + f) * 512, vb_ + (qs4 + f) * 1024);                  \
  } while (0)
// one iteration: counted-vmcnt + raw barrier, then prefetch/QK/SM/PV
#define BODY(T, CUR, PREFETCH) do {                                           \
    asm volatile("s_waitcnt vmcnt(4)" ::: "memory");  /* stage(T) done */     \
    __builtin_amdgcn_s_barrier();                     /* both stagers done */ \
    if (PREFETCH) STAGEV((T) + 1, (CUR) ^ 1);                                 \
    f32x4 sa[2], sb[2];                                                       \
    __builtin_amdgcn_s_setprio(1);                                            \
    _Pragma("unroll") for (int h = 0; h < 2; ++h) {                           \
      sa[h] = __builtin_amdgcn_mfma_f32_16x16x32_bf16(kf[0][0], qf[h][0], fzero, 0, 0, 0); \
      sa[h] = __builtin_amdgcn_mfma_f32_16x16x32_bf16(kf[0][1], qf[h][1], sa[h], 0, 0, 0); \
      sb[h] = __builtin_amdgcn_mfma_f32_16x16x32_bf16(kf[1][0], qf[h][0], fzero, 0, 0, 0); \
      sb[h] = __builtin_amdgcn_mfma_f32_16x16x32_bf16(kf[1][1], qf[h][1], sb[h], 0, 0, 0); \
    }                                                                         \
    __builtin_amdgcn_s_setprio(0);                                            \
    if (PREFETCH) KLOAD((T) + 1);                                             \
    bf16x8 pf[2];                                                             \
    _Pragma("unroll") for (int h = 0; h < 2; ++h) {                           \
      const float p0 = __builtin_amdgcn_exp2f(sa[h][0]);                      \
      const float p1 = __builtin_amdgcn_exp2f(sa[h][1]);                      \
      const float p2 = __builtin_amdgcn_exp2f(sa[h][2]);                      \
      const float p3 = __builtin_amdgcn_exp2f(sa[h][3]);                      \
      const float p4 = __builtin_amdgcn_exp2f(sb[h][0]);                      \
      const float p5 = __builtin_amdgcn_exp2f(sb[h][1]);                      \
      const float p6 = __builtin_amdgcn_exp2f(sb[h][2]);                      \
      const float p7 = __builtin_amdgcn_exp2f(sb[h][3]);                      \
      lrow[h] += ((p0 + p1) + (p2 + p3)) + ((p4 + p5) + (p6 + p7));           \
      u32x4v pk;                                                              \
      pk[0] = cvt_pk_bf16(p0, p1);                                            \
      pk[1] = cvt_pk_bf16(p2, p3);                                            \
      pk[2] = cvt_pk_bf16(p4, p5);                                            \
      pk[3] = cvt_pk_bf16(p6, p7);                                            \
      pf[h] = __builtin_bit_cast(bf16x8, pk);                                 \
    }                                                                         \
    const char* vb = vlds + (CUR) * 8192;                                     \
    __builtin_amdgcn_s_setprio(1);                                            \
    _Pragma("unroll") for (int dt = 0; dt < 8; ++dt) {                        \
      const bf16x8 vf = *(const bf16x8*)(vb + dt * 1024 + vq);                \
      _Pragma("unroll") for (int h = 0; h < 2; ++h)                           \
        oacc[h][dt] = __builtin_amdgcn_mfma_f32_16x16x32_bf16(vf, pf[h], oacc[h][dt], 0, 0, 0); \
    }                                                                         \
    __builtin_amdgcn_s_setprio(0);                                            \
  } while (0)

  const int t0 = kvh * 64;                 // this wave's first kv tile (64 tiles)
  STAGEV(t0, 0);                           // V(t) always issued BEFORE K(t)
  KLOAD(t0);

  #pragma unroll 1
  for (int i = 0; i < 63; ++i) {
    BODY(t0 + i, i & 1, 1);
  }
  BODY(t0 + 63, 1, 0);                     // peeled final iteration (63&1 = 1)

  // ---- epilogue: per-qw pair merge (kvh=1 dumps, kvh=0 combines) ----
  #pragma unroll
  for (int h = 0; h < 2; ++h) {            // reduce l over lg groups
    lrow[h] += __shfl_xor(lrow[h], 16, 64);
    lrow[h] += __shfl_xor(lrow[h], 32, 64);
  }
  float* const mybuf = (float*)(lds + qw * 16896);   // [128 dv][33] f32
  float* const stats = (float*)(lds + 33792);        // [2 qw][2 h][16 li]
  __syncthreads();                          // V bufs dead; epilogue regions live
  if (kvh == 1) {
    if (lg == 0) {
      #pragma unroll
      for (int h = 0; h < 2; ++h) stats[qw * 32 + h * 16 + li] = lrow[h];
    }
    #pragma unroll
    for (int h = 0; h < 2; ++h)
      #pragma unroll
      for (int dt = 0; dt < 8; ++dt)
        #pragma unroll
        for (int r = 0; r < 4; ++r)
          mybuf[(dt * 16 + lg * 4 + r) * 33 + h * 16 + li] = oacc[h][dt][r];
  }
  __syncthreads();
  if (kvh == 0) {
    #pragma unroll
    for (int h = 0; h < 2; ++h) {
      const float ls = lrow[h] + stats[qw * 32 + h * 16 + li];
      const float rl = 1.0f / ls;
      #pragma unroll
      for (int dt = 0; dt < 8; ++dt) {
        #pragma unroll
        for (int r = 0; r < 4; ++r) {
          const int dv = dt * 16 + lg * 4 + r;
          const float oB = mybuf[dv * 33 + h * 16 + li];
          const size_t idx = ((size_t)b * DVV + dv) * NSEQ + qbase + h * 16 + li;
          out[idx] = (oacc[h][dt][r] + oB) * rl + x[idx];
        }
      }
    }
  }
#undef KLOAD
#undef STAGEV
#undef BODY
}

extern "C" void kernel_launch(void* const* d_in, const int* in_sizes, int n_in,
                              void* d_out, int out_size, void* d_ws, size_t ws_size,
                              hipStream_t stream) {
  const float* x  = (const float*)d_in[0];
  const float* Wq = (const float*)d_in[1];
  const float* Wk = (const float*)d_in[2];
  const float* Wv = (const float*)d_in[3];
  float* out = (float*)d_out;

  u16* qws = (u16*)d_ws;                                   // [8][4096][64]   4MB
  u16* kws = qws + (size_t)NB * NSEQ * DK;                 // Kf frag-linear  4MB
  u16* vws = kws + (size_t)NB * NSEQ * DK;                 // Vf frag-linear  8MB

  proj<<<512, 256, 0, stream>>>(x, Wq, Wk, Wv, qws, kws, vws);
  attn<<<512, 256, 0, stream>>>(qws, kws, vws, x, out);
}